// Round 1
// baseline (471.938 us; speedup 1.0000x reference)
//
#include <hip/hip_runtime.h>
#include <stdint.h>

#define NROWS 8192
#define DDIM  256
#define K3    768          // [hi | hi | lo] x [hi | lo | hi] K-concatenation
#define MARGIN_F 0.2f

typedef short  short8  __attribute__((ext_vector_type(8)));
typedef float  floatx4 __attribute__((ext_vector_type(4)));

// Static device buffers (avoid depending on ws_size).
__device__ unsigned short gA[(size_t)NROWS * K3];   // im split: [hi | hi | lo]
__device__ unsigned short gB[(size_t)NROWS * K3];   // s  split: [hi | lo | hi]
__device__ float    g_diag[NROWS];
__device__ unsigned g_rowcnt[NROWS];
__device__ unsigned g_rowkey[NROWS];
__device__ unsigned g_colcnt[NROWS];
__device__ unsigned g_colkey[NROWS];

__device__ __forceinline__ unsigned short f2bf_rne(float x){
    unsigned u = __float_as_uint(x);
    return (unsigned short)((u + 0x7FFFu + ((u >> 16) & 1u)) >> 16);
}
__device__ __forceinline__ float bf2f(unsigned short h){
    return __uint_as_float(((unsigned)h) << 16);
}
// monotone float -> uint key (order-preserving), so atomicMax works on floats
__device__ __forceinline__ unsigned fkey(float f){
    unsigned u = __float_as_uint(f);
    return (u & 0x80000000u) ? ~u : (u | 0x80000000u);
}
__device__ __forceinline__ float kinv(unsigned k){
    unsigned u = (k & 0x80000000u) ? (k ^ 0x80000000u) : ~k;
    return __uint_as_float(u);
}

// One wave per row: fp32 diag dot, hi/lo bf16 split, stats init.
__global__ __launch_bounds__(256) void prep_kernel(const float* __restrict__ im,
                                                   const float* __restrict__ s){
    const int w    = threadIdx.x >> 6;
    const int lane = threadIdx.x & 63;
    const int row  = blockIdx.x * 4 + w;

    const float4 a = ((const float4*)(im + (size_t)row * DDIM))[lane];
    const float4 b = ((const float4*)(s  + (size_t)row * DDIM))[lane];

    float dp = a.x*b.x + a.y*b.y + a.z*b.z + a.w*b.w;
    #pragma unroll
    for (int m = 1; m < 64; m <<= 1) dp += __shfl_xor(dp, m, 64);
    if (lane == 0){
        g_diag[row]   = dp;
        g_rowcnt[row] = 0u; g_rowkey[row] = 0u;
        g_colcnt[row] = 0u; g_colkey[row] = 0u;
    }

    float av[4] = {a.x, a.y, a.z, a.w};
    float bv[4] = {b.x, b.y, b.z, b.w};
    unsigned short ah[4], al[4], bh[4], bl[4];
    #pragma unroll
    for (int i = 0; i < 4; ++i){
        ah[i] = f2bf_rne(av[i]); al[i] = f2bf_rne(av[i] - bf2f(ah[i]));
        bh[i] = f2bf_rne(bv[i]); bl[i] = f2bf_rne(bv[i] - bf2f(bh[i]));
    }
    const size_t base = (size_t)row * K3 + lane * 4;
    *(ushort4*)&gA[base      ] = make_ushort4(ah[0], ah[1], ah[2], ah[3]);
    *(ushort4*)&gA[base + 256] = make_ushort4(ah[0], ah[1], ah[2], ah[3]);
    *(ushort4*)&gA[base + 512] = make_ushort4(al[0], al[1], al[2], al[3]);
    *(ushort4*)&gB[base      ] = make_ushort4(bh[0], bh[1], bh[2], bh[3]);
    *(ushort4*)&gB[base + 256] = make_ushort4(bl[0], bl[1], bl[2], bl[3]);
    *(ushort4*)&gB[base + 512] = make_ushort4(bh[0], bh[1], bh[2], bh[3]);
}

// 128x128 tile, 4 waves (2x2), 16x16x32 bf16 MFMA, BK=64, global_load_lds(16B).
// Fused epilogue: per-row / per-col count(v<diag) and off-diagonal max via atomics.
__global__ __launch_bounds__(256) void gemm_stats_kernel(){
    __shared__ unsigned short As[128 * 64];
    __shared__ unsigned short Bs[128 * 64];
    __shared__ float drow[128];
    __shared__ float dcol[128];

    const int tid = threadIdx.x;
    const int bi = blockIdx.y, bj = blockIdx.x;

    if (tid < 128) drow[tid]       = g_diag[bi * 128 + tid];
    else           dcol[tid - 128] = g_diag[bj * 128 + (tid - 128)];

    const int w    = tid >> 6, lane = tid & 63;
    const int wm   = w >> 1,   wn   = w & 1;
    const int quad = lane >> 4, l16 = lane & 15;

    floatx4 acc[4][4] = {};

    const unsigned short* Abase = gA + (size_t)bi * 128 * K3;
    const unsigned short* Bbase = gB + (size_t)bj * 128 * K3;

    for (int kk = 0; kk < K3; kk += 64){
        #pragma unroll
        for (int q = 0; q < 4; ++q){
            const int o = q * 4096 + tid * 16;   // byte offset into 16KB tile
            const int r = o >> 7;                // tile row
            const int c = (o & 127) >> 1;        // element col within 64
            __builtin_amdgcn_global_load_lds(
                (const __attribute__((address_space(1))) unsigned int*)(uintptr_t)(Abase + (size_t)r * K3 + kk + c),
                (__attribute__((address_space(3))) unsigned int*)(unsigned)(uintptr_t)((char*)As + o),
                16, 0, 0);
            __builtin_amdgcn_global_load_lds(
                (const __attribute__((address_space(1))) unsigned int*)(uintptr_t)(Bbase + (size_t)r * K3 + kk + c),
                (__attribute__((address_space(3))) unsigned int*)(unsigned)(uintptr_t)((char*)Bs + o),
                16, 0, 0);
        }
        __syncthreads();
        #pragma unroll
        for (int ks = 0; ks < 2; ++ks){
            short8 af[4], bfr[4];
            #pragma unroll
            for (int mi = 0; mi < 4; ++mi)
                af[mi] = *(const short8*)&As[(wm * 64 + mi * 16 + l16) * 64 + ks * 32 + quad * 8];
            #pragma unroll
            for (int nj = 0; nj < 4; ++nj)
                bfr[nj] = *(const short8*)&Bs[(wn * 64 + nj * 16 + l16) * 64 + ks * 32 + quad * 8];
            #pragma unroll
            for (int mi = 0; mi < 4; ++mi)
                #pragma unroll
                for (int nj = 0; nj < 4; ++nj)
                    acc[mi][nj] = __builtin_amdgcn_mfma_f32_16x16x32_bf16(af[mi], bfr[nj], acc[mi][nj], 0, 0, 0);
        }
        __syncthreads();
    }

    // ---- fused stats epilogue ----
    // C/D layout (verified m89/m91): col = lane&15, row = quad*4 + reg.
    const int colbase = bj * 128 + wn * 64;
    const int rowbase = bi * 128 + wm * 64;

    // row stats: reduce across cols (lanes differing in bits 0..3)
    #pragma unroll
    for (int mi = 0; mi < 4; ++mi){
        #pragma unroll
        for (int r = 0; r < 4; ++r){
            const int lrow = wm * 64 + mi * 16 + quad * 4 + r;
            const int gi   = bi * 128 + lrow;
            const float dv = drow[lrow];
            int cnt = 0; float mx = -3.0e38f;
            #pragma unroll
            for (int nj = 0; nj < 4; ++nj){
                const float v  = acc[mi][nj][r];
                const int   gj = colbase + nj * 16 + l16;
                if (gi != gj){                 // exclude diagonal explicitly
                    cnt += (v < dv) ? 1 : 0;
                    mx = fmaxf(mx, v);
                }
            }
            #pragma unroll
            for (int m = 1; m < 16; m <<= 1){
                cnt += __shfl_xor(cnt, m, 64);
                mx   = fmaxf(mx, __shfl_xor(mx, m, 64));
            }
            if (l16 == 0){
                atomicAdd(&g_rowcnt[gi], (unsigned)cnt);
                atomicMax(&g_rowkey[gi], fkey(mx));
            }
        }
    }
    // col stats: reduce across rows (lanes differing in bits 4..5, plus regs)
    #pragma unroll
    for (int nj = 0; nj < 4; ++nj){
        const int lcol = wn * 64 + nj * 16 + l16;
        const int gj   = bj * 128 + lcol;
        const float dv = dcol[lcol];
        int cnt = 0; float mx = -3.0e38f;
        #pragma unroll
        for (int mi = 0; mi < 4; ++mi){
            #pragma unroll
            for (int r = 0; r < 4; ++r){
                const float v  = acc[mi][nj][r];
                const int   gi = rowbase + mi * 16 + quad * 4 + r;
                if (gi != gj){
                    cnt += (v < dv) ? 1 : 0;
                    mx = fmaxf(mx, v);
                }
            }
        }
        #pragma unroll
        for (int m = 16; m < 64; m <<= 1){
            cnt += __shfl_xor(cnt, m, 64);
            mx   = fmaxf(mx, __shfl_xor(mx, m, 64));
        }
        if (quad == 0){
            atomicAdd(&g_colcnt[gj], (unsigned)cnt);
            atomicMax(&g_colkey[gj], fkey(mx));
        }
    }
}

__global__ __launch_bounds__(256) void finalize_kernel(float* __restrict__ out){
    __shared__ double red[256];
    double acc = 0.0;
    for (int i = threadIdx.x; i < NROWS; i += 256){
        const float d  = g_diag[i];
        const float cs  = fmaxf(MARGIN_F + kinv(g_rowkey[i]) - d, 0.0f) * (1.0f / (float)(g_rowcnt[i] + 1u));
        const float cim = fmaxf(MARGIN_F + kinv(g_colkey[i]) - d, 0.0f) * (1.0f / (float)(g_colcnt[i] + 1u));
        acc += (double)cs + (double)cim;
    }
    red[threadIdx.x] = acc;
    __syncthreads();
    for (int s2 = 128; s2 > 0; s2 >>= 1){
        if (threadIdx.x < s2) red[threadIdx.x] += red[threadIdx.x + s2];
        __syncthreads();
    }
    if (threadIdx.x == 0) out[0] = (float)red[0];
}

extern "C" void kernel_launch(void* const* d_in, const int* in_sizes, int n_in,
                              void* d_out, int out_size, void* d_ws, size_t ws_size,
                              hipStream_t stream){
    const float* im = (const float*)d_in[0];
    const float* s  = (const float*)d_in[1];
    float* out = (float*)d_out;

    prep_kernel<<<NROWS / 4, 256, 0, stream>>>(im, s);
    dim3 grid(64, 64);
    gemm_stats_kernel<<<grid, 256, 0, stream>>>();
    finalize_kernel<<<1, 256, 0, stream>>>(out);
}

// Round 2
// 370.360 us; speedup vs baseline: 1.2743x; 1.2743x over previous
//
#include <hip/hip_runtime.h>
#include <stdint.h>

#define NROWS 8192
#define DDIM  256
#define K3    768          // [hi | hi | lo] x [hi | lo | hi] K-concatenation
#define MARGIN_F 0.2f

typedef short  short8  __attribute__((ext_vector_type(8)));
typedef float  floatx4 __attribute__((ext_vector_type(4)));

// Static device buffers (avoid depending on ws_size).
__device__ unsigned short gA[(size_t)NROWS * K3];   // im split: [hi | hi | lo]
__device__ unsigned short gB[(size_t)NROWS * K3];   // s  split: [hi | lo | hi]
__device__ float    g_diag[NROWS];
__device__ unsigned g_rowcnt[NROWS];
__device__ unsigned g_rowkey[NROWS];
__device__ unsigned g_colcnt[NROWS];
__device__ unsigned g_colkey[NROWS];

__device__ __forceinline__ unsigned short f2bf_rne(float x){
    unsigned u = __float_as_uint(x);
    return (unsigned short)((u + 0x7FFFu + ((u >> 16) & 1u)) >> 16);
}
__device__ __forceinline__ float bf2f(unsigned short h){
    return __uint_as_float(((unsigned)h) << 16);
}
// monotone float -> uint key (order-preserving), so atomicMax works on floats
__device__ __forceinline__ unsigned fkey(float f){
    unsigned u = __float_as_uint(f);
    return (u & 0x80000000u) ? ~u : (u | 0x80000000u);
}
__device__ __forceinline__ float kinv(unsigned k){
    unsigned u = (k & 0x80000000u) ? (k ^ 0x80000000u) : ~k;
    return __uint_as_float(u);
}

// One wave per row: fp32 diag dot, hi/lo bf16 split, stats init.
__global__ __launch_bounds__(256) void prep_kernel(const float* __restrict__ im,
                                                   const float* __restrict__ s){
    const int w    = threadIdx.x >> 6;
    const int lane = threadIdx.x & 63;
    const int row  = blockIdx.x * 4 + w;

    const float4 a = ((const float4*)(im + (size_t)row * DDIM))[lane];
    const float4 b = ((const float4*)(s  + (size_t)row * DDIM))[lane];

    float dp = a.x*b.x + a.y*b.y + a.z*b.z + a.w*b.w;
    #pragma unroll
    for (int m = 1; m < 64; m <<= 1) dp += __shfl_xor(dp, m, 64);
    if (lane == 0){
        g_diag[row]   = dp;
        g_rowcnt[row] = 0u; g_rowkey[row] = 0u;
        g_colcnt[row] = 0u; g_colkey[row] = 0u;
    }

    float av[4] = {a.x, a.y, a.z, a.w};
    float bv[4] = {b.x, b.y, b.z, b.w};
    unsigned short ah[4], al[4], bh[4], bl[4];
    #pragma unroll
    for (int i = 0; i < 4; ++i){
        ah[i] = f2bf_rne(av[i]); al[i] = f2bf_rne(av[i] - bf2f(ah[i]));
        bh[i] = f2bf_rne(bv[i]); bl[i] = f2bf_rne(bv[i] - bf2f(bh[i]));
    }
    const size_t base = (size_t)row * K3 + lane * 4;
    *(ushort4*)&gA[base      ] = make_ushort4(ah[0], ah[1], ah[2], ah[3]);
    *(ushort4*)&gA[base + 256] = make_ushort4(ah[0], ah[1], ah[2], ah[3]);
    *(ushort4*)&gA[base + 512] = make_ushort4(al[0], al[1], al[2], al[3]);
    *(ushort4*)&gB[base      ] = make_ushort4(bh[0], bh[1], bh[2], bh[3]);
    *(ushort4*)&gB[base + 256] = make_ushort4(bl[0], bl[1], bl[2], bl[3]);
    *(ushort4*)&gB[base + 512] = make_ushort4(bh[0], bh[1], bh[2], bh[3]);
}

// 128x128 tile, 4 waves (2x2), 16x16x32 bf16 MFMA, BK=64, global_load_lds(16B).
// LDS XOR-swizzle at 16B-chunk granularity: logical (row, c) stored at
// (row, c ^ (row&7)). Applied on the GLOBAL address side during staging
// (global_load_lds's LDS side is fixed to uniform-base + lane*16), and on the
// read side it reduces to c_st = (ks*4+quad) ^ (l16&7) -> 2-way bank aliasing
// (free) instead of 16-way conflicts.
__global__ __launch_bounds__(256) void gemm_stats_kernel(){
    __shared__ unsigned short As[128 * 64];
    __shared__ unsigned short Bs[128 * 64];
    __shared__ float drow[128];
    __shared__ float dcol[128];

    const int tid = threadIdx.x;

    // 16x16 supertile remap of the 64x64 tile grid for L2/L3 locality:
    // 256 consecutive blocks cover a 16x16 square of tiles (3.1MB A + 3.1MB B).
    const int lin = blockIdx.x;
    const int st  = lin >> 8;           // supertile 0..15
    const int loc = lin & 255;
    const int bi  = (st >> 2) * 16 + (loc >> 4);
    const int bj  = (st & 3)  * 16 + (loc & 15);

    if (tid < 128) drow[tid]       = g_diag[bi * 128 + tid];
    else           dcol[tid - 128] = g_diag[bj * 128 + (tid - 128)];

    const int w    = tid >> 6, lane = tid & 63;
    const int wm   = w >> 1,   wn   = w & 1;
    const int quad = lane >> 4, l16 = lane & 15;
    const int sw   = l16 & 7;           // read-side swizzle key

    floatx4 acc[4][4] = {};

    const unsigned short* Abase = gA + (size_t)bi * 128 * K3;
    const unsigned short* Bbase = gB + (size_t)bj * 128 * K3;

    for (int kk = 0; kk < K3; kk += 64){
        #pragma unroll
        for (int q = 0; q < 4; ++q){
            const int o    = q * 4096 + tid * 16;     // LDS byte offset (fixed)
            const int ch   = o >> 4;                  // linear chunk index
            const int r    = ch >> 3;                 // tile row
            const int cst  = ch & 7;                  // stored chunk pos
            const int clog = cst ^ (r & 7);           // logical chunk -> global
            const size_t goff = (size_t)r * K3 + kk + clog * 8;
            __builtin_amdgcn_global_load_lds(
                (const __attribute__((address_space(1))) unsigned int*)(uintptr_t)(Abase + goff),
                (__attribute__((address_space(3))) unsigned int*)(unsigned)(uintptr_t)((char*)As + o),
                16, 0, 0);
            __builtin_amdgcn_global_load_lds(
                (const __attribute__((address_space(1))) unsigned int*)(uintptr_t)(Bbase + goff),
                (__attribute__((address_space(3))) unsigned int*)(unsigned)(uintptr_t)((char*)Bs + o),
                16, 0, 0);
        }
        __syncthreads();
        #pragma unroll
        for (int ks = 0; ks < 2; ++ks){
            short8 af[4], bfr[4];
            #pragma unroll
            for (int mi = 0; mi < 4; ++mi)
                af[mi] = *(const short8*)&As[(wm * 64 + mi * 16 + l16) * 64 + (((ks * 4 + quad) ^ sw) * 8)];
            #pragma unroll
            for (int nj = 0; nj < 4; ++nj)
                bfr[nj] = *(const short8*)&Bs[(wn * 64 + nj * 16 + l16) * 64 + (((ks * 4 + quad) ^ sw) * 8)];
            #pragma unroll
            for (int mi = 0; mi < 4; ++mi)
                #pragma unroll
                for (int nj = 0; nj < 4; ++nj)
                    acc[mi][nj] = __builtin_amdgcn_mfma_f32_16x16x32_bf16(af[mi], bfr[nj], acc[mi][nj], 0, 0, 0);
        }
        __syncthreads();
    }

    // ---- fused stats epilogue ----
    // C/D layout (verified m89/m91): col = lane&15, row = quad*4 + reg.
    const int colbase = bj * 128 + wn * 64;
    const int rowbase = bi * 128 + wm * 64;

    // row stats: reduce across cols (lanes differing in bits 0..3)
    #pragma unroll
    for (int mi = 0; mi < 4; ++mi){
        #pragma unroll
        for (int r = 0; r < 4; ++r){
            const int lrow = wm * 64 + mi * 16 + quad * 4 + r;
            const int gi   = bi * 128 + lrow;
            const float dv = drow[lrow];
            int cnt = 0; float mx = -3.0e38f;
            #pragma unroll
            for (int nj = 0; nj < 4; ++nj){
                const float v  = acc[mi][nj][r];
                const int   gj = colbase + nj * 16 + l16;
                if (gi != gj){                 // exclude diagonal explicitly
                    cnt += (v < dv) ? 1 : 0;
                    mx = fmaxf(mx, v);
                }
            }
            #pragma unroll
            for (int m = 1; m < 16; m <<= 1){
                cnt += __shfl_xor(cnt, m, 64);
                mx   = fmaxf(mx, __shfl_xor(mx, m, 64));
            }
            if (l16 == 0){
                atomicAdd(&g_rowcnt[gi], (unsigned)cnt);
                atomicMax(&g_rowkey[gi], fkey(mx));
            }
        }
    }
    // col stats: reduce across rows (lanes differing in bits 4..5, plus regs)
    #pragma unroll
    for (int nj = 0; nj < 4; ++nj){
        const int lcol = wn * 64 + nj * 16 + l16;
        const int gj   = bj * 128 + lcol;
        const float dv = dcol[lcol];
        int cnt = 0; float mx = -3.0e38f;
        #pragma unroll
        for (int mi = 0; mi < 4; ++mi){
            #pragma unroll
            for (int r = 0; r < 4; ++r){
                const float v  = acc[mi][nj][r];
                const int   gi = rowbase + mi * 16 + quad * 4 + r;
                if (gi != gj){
                    cnt += (v < dv) ? 1 : 0;
                    mx = fmaxf(mx, v);
                }
            }
        }
        #pragma unroll
        for (int m = 16; m < 64; m <<= 1){
            cnt += __shfl_xor(cnt, m, 64);
            mx   = fmaxf(mx, __shfl_xor(mx, m, 64));
        }
        if (quad == 0){
            atomicAdd(&g_colcnt[gj], (unsigned)cnt);
            atomicMax(&g_colkey[gj], fkey(mx));
        }
    }
}

__global__ __launch_bounds__(256) void finalize_kernel(float* __restrict__ out){
    __shared__ double red[256];
    double acc = 0.0;
    for (int i = threadIdx.x; i < NROWS; i += 256){
        const float d  = g_diag[i];
        const float cs  = fmaxf(MARGIN_F + kinv(g_rowkey[i]) - d, 0.0f) * (1.0f / (float)(g_rowcnt[i] + 1u));
        const float cim = fmaxf(MARGIN_F + kinv(g_colkey[i]) - d, 0.0f) * (1.0f / (float)(g_colcnt[i] + 1u));
        acc += (double)cs + (double)cim;
    }
    red[threadIdx.x] = acc;
    __syncthreads();
    for (int s2 = 128; s2 > 0; s2 >>= 1){
        if (threadIdx.x < s2) red[threadIdx.x] += red[threadIdx.x + s2];
        __syncthreads();
    }
    if (threadIdx.x == 0) out[0] = (float)red[0];
}

extern "C" void kernel_launch(void* const* d_in, const int* in_sizes, int n_in,
                              void* d_out, int out_size, void* d_ws, size_t ws_size,
                              hipStream_t stream){
    const float* im = (const float*)d_in[0];
    const float* s  = (const float*)d_in[1];
    float* out = (float*)d_out;

    prep_kernel<<<NROWS / 4, 256, 0, stream>>>(im, s);
    gemm_stats_kernel<<<4096, 256, 0, stream>>>();
    finalize_kernel<<<1, 256, 0, stream>>>(out);
}

// Round 3
// 293.798 us; speedup vs baseline: 1.6063x; 1.2606x over previous
//
#include <hip/hip_runtime.h>
#include <stdint.h>

#define NROWS 8192
#define DDIM  256
#define K2    512          // [hi | lo] packed per row
#define MARGIN_F 0.2f

typedef short  short8  __attribute__((ext_vector_type(8)));
typedef float  floatx4 __attribute__((ext_vector_type(4)));

// Static device buffers (avoid depending on ws_size).
__device__ unsigned short gA[(size_t)NROWS * K2];   // im split: [hi | lo]
__device__ unsigned short gB[(size_t)NROWS * K2];   // s  split: [hi | lo]
__device__ float    g_diag[NROWS];
__device__ unsigned g_rowcnt[NROWS];
__device__ unsigned g_rowkey[NROWS];
__device__ unsigned g_colcnt[NROWS];
__device__ unsigned g_colkey[NROWS];

__device__ __forceinline__ unsigned short f2bf_rne(float x){
    unsigned u = __float_as_uint(x);
    return (unsigned short)((u + 0x7FFFu + ((u >> 16) & 1u)) >> 16);
}
__device__ __forceinline__ float bf2f(unsigned short h){
    return __uint_as_float(((unsigned)h) << 16);
}
// monotone float -> uint key (order-preserving), so atomicMax works on floats
__device__ __forceinline__ unsigned fkey(float f){
    unsigned u = __float_as_uint(f);
    return (u & 0x80000000u) ? ~u : (u | 0x80000000u);
}
__device__ __forceinline__ float kinv(unsigned k){
    unsigned u = (k & 0x80000000u) ? (k ^ 0x80000000u) : ~k;
    return __uint_as_float(u);
}

__device__ __forceinline__ void load_lds16(const unsigned short* gptr, void* lptr){
    __builtin_amdgcn_global_load_lds(
        (const __attribute__((address_space(1))) unsigned int*)(uintptr_t)gptr,
        (__attribute__((address_space(3))) unsigned int*)(unsigned)(uintptr_t)lptr,
        16, 0, 0);
}

// One wave per row: fp32 diag dot, hi/lo bf16 split, stats init.
__global__ __launch_bounds__(256) void prep_kernel(const float* __restrict__ im,
                                                   const float* __restrict__ s){
    const int w    = threadIdx.x >> 6;
    const int lane = threadIdx.x & 63;
    const int row  = blockIdx.x * 4 + w;

    const float4 a = ((const float4*)(im + (size_t)row * DDIM))[lane];
    const float4 b = ((const float4*)(s  + (size_t)row * DDIM))[lane];

    float dp = a.x*b.x + a.y*b.y + a.z*b.z + a.w*b.w;
    #pragma unroll
    for (int m = 1; m < 64; m <<= 1) dp += __shfl_xor(dp, m, 64);
    if (lane == 0){
        g_diag[row]   = dp;
        g_rowcnt[row] = 0u; g_rowkey[row] = 0u;
        g_colcnt[row] = 0u; g_colkey[row] = 0u;
    }

    float av[4] = {a.x, a.y, a.z, a.w};
    float bv[4] = {b.x, b.y, b.z, b.w};
    unsigned short ah[4], al[4], bh[4], bl[4];
    #pragma unroll
    for (int i = 0; i < 4; ++i){
        ah[i] = f2bf_rne(av[i]); al[i] = f2bf_rne(av[i] - bf2f(ah[i]));
        bh[i] = f2bf_rne(bv[i]); bl[i] = f2bf_rne(bv[i] - bf2f(bh[i]));
    }
    const size_t base = (size_t)row * K2 + lane * 4;
    *(ushort4*)&gA[base      ] = make_ushort4(ah[0], ah[1], ah[2], ah[3]);
    *(ushort4*)&gA[base + 256] = make_ushort4(al[0], al[1], al[2], al[3]);
    *(ushort4*)&gB[base      ] = make_ushort4(bh[0], bh[1], bh[2], bh[3]);
    *(ushort4*)&gB[base + 256] = make_ushort4(bl[0], bl[1], bl[2], bl[3]);
}

// 128x128 tile, 4 waves (2x2), 16x16x32 bf16 MFMA, BK=64 chunks over K=256.
// Non-redundant staging: per chunk hold Ah (T1), Bh (T2), and T3 = Bl then Al.
//   stage Ah,Bh,Bl -> 64 MFMA (Ah*Bh + Ah*Bl) -> stage Al into T3 -> 32 MFMA (Al*Bh)
// 256 KB staged per block (was 384 KB). LDS XOR-swizzle at 16B-chunk
// granularity (global-side inverse, read-side c ^ (l16&7)) -> 0 bank conflicts.
// XCD-aware block swizzle: bid&7 selects an 8-row tile band, traversed
// column-major, so each XCD's L2 holds its A band (~1MB) + streaming B cols.
__global__ __launch_bounds__(256) void gemm_stats_kernel(){
    __shared__ unsigned short T1[128 * 64];   // Ah chunk
    __shared__ unsigned short T2[128 * 64];   // Bh chunk
    __shared__ unsigned short T3[128 * 64];   // Bl, then Al
    __shared__ float drow[128];
    __shared__ float dcol[128];

    const int tid = threadIdx.x;
    const int bid = blockIdx.x;
    // bid[2:0]->band(XCD), bid[5:3]->row within band, bid[11:6]->column
    const int bi  = (bid & 7) * 8 + ((bid >> 3) & 7);
    const int bj  = bid >> 6;

    if (tid < 128) drow[tid]       = g_diag[bi * 128 + tid];
    else           dcol[tid - 128] = g_diag[bj * 128 + (tid - 128)];

    const int w    = tid >> 6, lane = tid & 63;
    const int wm   = w >> 1,   wn   = w & 1;
    const int quad = lane >> 4, l16 = lane & 15;
    const int sw   = l16 & 7;           // read-side swizzle key

    floatx4 acc[4][4] = {};

    const unsigned short* Abase = gA + (size_t)bi * 128 * K2;
    const unsigned short* Bbase = gB + (size_t)bj * 128 * K2;

    for (int kc = 0; kc < 4; ++kc){
        // ---- stage Ah -> T1, Bh -> T2, Bl -> T3 ----
        #pragma unroll
        for (int q = 0; q < 4; ++q){
            const int o    = q * 4096 + tid * 16;     // LDS byte offset (fixed)
            const int ch   = o >> 4;                  // linear chunk index
            const int r    = ch >> 3;                 // tile row
            const int clog = (ch & 7) ^ (r & 7);      // stored -> logical chunk
            const size_t goff = (size_t)r * K2 + kc * 64 + clog * 8;
            load_lds16(Abase + goff,       (char*)T1 + o);
            load_lds16(Bbase + goff,       (char*)T2 + o);
            load_lds16(Bbase + goff + 256, (char*)T3 + o);
        }
        __syncthreads();
        // ---- pass 1+2: Ah*Bh + Ah*Bl ----
        #pragma unroll
        for (int ks = 0; ks < 2; ++ks){
            const int co = ((ks * 4 + quad) ^ sw) * 8;
            short8 ahf[4], bhf[4], blf[4];
            #pragma unroll
            for (int mi = 0; mi < 4; ++mi)
                ahf[mi] = *(const short8*)&T1[(wm * 64 + mi * 16 + l16) * 64 + co];
            #pragma unroll
            for (int nj = 0; nj < 4; ++nj){
                bhf[nj] = *(const short8*)&T2[(wn * 64 + nj * 16 + l16) * 64 + co];
                blf[nj] = *(const short8*)&T3[(wn * 64 + nj * 16 + l16) * 64 + co];
            }
            #pragma unroll
            for (int mi = 0; mi < 4; ++mi)
                #pragma unroll
                for (int nj = 0; nj < 4; ++nj)
                    acc[mi][nj] = __builtin_amdgcn_mfma_f32_16x16x32_bf16(ahf[mi], bhf[nj], acc[mi][nj], 0, 0, 0);
            #pragma unroll
            for (int mi = 0; mi < 4; ++mi)
                #pragma unroll
                for (int nj = 0; nj < 4; ++nj)
                    acc[mi][nj] = __builtin_amdgcn_mfma_f32_16x16x32_bf16(ahf[mi], blf[nj], acc[mi][nj], 0, 0, 0);
        }
        __syncthreads();
        // ---- stage Al -> T3 ----
        #pragma unroll
        for (int q = 0; q < 4; ++q){
            const int o    = q * 4096 + tid * 16;
            const int ch   = o >> 4;
            const int r    = ch >> 3;
            const int clog = (ch & 7) ^ (r & 7);
            const size_t goff = (size_t)r * K2 + kc * 64 + clog * 8;
            load_lds16(Abase + goff + 256, (char*)T3 + o);
        }
        __syncthreads();
        // ---- pass 3: Al*Bh ----
        #pragma unroll
        for (int ks = 0; ks < 2; ++ks){
            const int co = ((ks * 4 + quad) ^ sw) * 8;
            short8 alf[4], bhf[4];
            #pragma unroll
            for (int mi = 0; mi < 4; ++mi)
                alf[mi] = *(const short8*)&T3[(wm * 64 + mi * 16 + l16) * 64 + co];
            #pragma unroll
            for (int nj = 0; nj < 4; ++nj)
                bhf[nj] = *(const short8*)&T2[(wn * 64 + nj * 16 + l16) * 64 + co];
            #pragma unroll
            for (int mi = 0; mi < 4; ++mi)
                #pragma unroll
                for (int nj = 0; nj < 4; ++nj)
                    acc[mi][nj] = __builtin_amdgcn_mfma_f32_16x16x32_bf16(alf[mi], bhf[nj], acc[mi][nj], 0, 0, 0);
        }
        __syncthreads();
    }

    // ---- fused stats epilogue ----
    // C/D layout (verified m89/m91): col = lane&15, row = quad*4 + reg.
    const int colbase = bj * 128 + wn * 64;
    const int rowbase = bi * 128 + wm * 64;

    // row stats: reduce across cols (lanes differing in bits 0..3)
    #pragma unroll
    for (int mi = 0; mi < 4; ++mi){
        #pragma unroll
        for (int r = 0; r < 4; ++r){
            const int lrow = wm * 64 + mi * 16 + quad * 4 + r;
            const int gi   = bi * 128 + lrow;
            const float dv = drow[lrow];
            int cnt = 0; float mx = -3.0e38f;
            #pragma unroll
            for (int nj = 0; nj < 4; ++nj){
                const float v  = acc[mi][nj][r];
                const int   gj = colbase + nj * 16 + l16;
                if (gi != gj){                 // exclude diagonal explicitly
                    cnt += (v < dv) ? 1 : 0;
                    mx = fmaxf(mx, v);
                }
            }
            #pragma unroll
            for (int m = 1; m < 16; m <<= 1){
                cnt += __shfl_xor(cnt, m, 64);
                mx   = fmaxf(mx, __shfl_xor(mx, m, 64));
            }
            if (l16 == 0){
                atomicAdd(&g_rowcnt[gi], (unsigned)cnt);
                atomicMax(&g_rowkey[gi], fkey(mx));
            }
        }
    }
    // col stats: reduce across rows (lanes differing in bits 4..5, plus regs)
    #pragma unroll
    for (int nj = 0; nj < 4; ++nj){
        const int lcol = wn * 64 + nj * 16 + l16;
        const int gj   = bj * 128 + lcol;
        const float dv = dcol[lcol];
        int cnt = 0; float mx = -3.0e38f;
        #pragma unroll
        for (int mi = 0; mi < 4; ++mi){
            #pragma unroll
            for (int r = 0; r < 4; ++r){
                const float v  = acc[mi][nj][r];
                const int   gi = rowbase + mi * 16 + quad * 4 + r;
                if (gi != gj){
                    cnt += (v < dv) ? 1 : 0;
                    mx = fmaxf(mx, v);
                }
            }
        }
        #pragma unroll
        for (int m = 16; m < 64; m <<= 1){
            cnt += __shfl_xor(cnt, m, 64);
            mx   = fmaxf(mx, __shfl_xor(mx, m, 64));
        }
        if (quad == 0){
            atomicAdd(&g_colcnt[gj], (unsigned)cnt);
            atomicMax(&g_colkey[gj], fkey(mx));
        }
    }
}

__global__ __launch_bounds__(256) void finalize_kernel(float* __restrict__ out){
    __shared__ double red[256];
    double acc = 0.0;
    for (int i = threadIdx.x; i < NROWS; i += 256){
        const float d  = g_diag[i];
        const float cs  = fmaxf(MARGIN_F + kinv(g_rowkey[i]) - d, 0.0f) * (1.0f / (float)(g_rowcnt[i] + 1u));
        const float cim = fmaxf(MARGIN_F + kinv(g_colkey[i]) - d, 0.0f) * (1.0f / (float)(g_colcnt[i] + 1u));
        acc += (double)cs + (double)cim;
    }
    red[threadIdx.x] = acc;
    __syncthreads();
    for (int s2 = 128; s2 > 0; s2 >>= 1){
        if (threadIdx.x < s2) red[threadIdx.x] += red[threadIdx.x + s2];
        __syncthreads();
    }
    if (threadIdx.x == 0) out[0] = (float)red[0];
}

extern "C" void kernel_launch(void* const* d_in, const int* in_sizes, int n_in,
                              void* d_out, int out_size, void* d_ws, size_t ws_size,
                              hipStream_t stream){
    const float* im = (const float*)d_in[0];
    const float* s  = (const float*)d_in[1];
    float* out = (float*)d_out;

    prep_kernel<<<NROWS / 4, 256, 0, stream>>>(im, s);
    gemm_stats_kernel<<<4096, 256, 0, stream>>>();
    finalize_kernel<<<1, 256, 0, stream>>>(out);
}

// Round 4
// 257.165 us; speedup vs baseline: 1.8352x; 1.1424x over previous
//
#include <hip/hip_runtime.h>
#include <stdint.h>

#define NROWS 8192
#define DDIM  256
#define K2    512          // [hi | lo] packed per row
#define MARGIN_F 0.2f

typedef short  short8  __attribute__((ext_vector_type(8)));
typedef float  floatx4 __attribute__((ext_vector_type(4)));

// Static device buffers (avoid depending on ws_size).
__device__ unsigned short gA[(size_t)NROWS * K2];   // im split: [hi | lo]
__device__ unsigned short gB[(size_t)NROWS * K2];   // s  split: [hi | lo]
__device__ float    g_diag[NROWS];
__device__ unsigned g_rowcnt[NROWS];
__device__ unsigned g_rowkey[NROWS];
__device__ unsigned g_colcnt[NROWS];
__device__ unsigned g_colkey[NROWS];

__device__ __forceinline__ unsigned short f2bf_rne(float x){
    unsigned u = __float_as_uint(x);
    return (unsigned short)((u + 0x7FFFu + ((u >> 16) & 1u)) >> 16);
}
__device__ __forceinline__ float bf2f(unsigned short h){
    return __uint_as_float(((unsigned)h) << 16);
}
// monotone float -> uint key (order-preserving), so atomicMax works on floats
__device__ __forceinline__ unsigned fkey(float f){
    unsigned u = __float_as_uint(f);
    return (u & 0x80000000u) ? ~u : (u | 0x80000000u);
}
__device__ __forceinline__ float kinv(unsigned k){
    unsigned u = (k & 0x80000000u) ? (k ^ 0x80000000u) : ~k;
    return __uint_as_float(u);
}

__device__ __forceinline__ void load_lds16(const unsigned short* gptr, void* lptr){
    __builtin_amdgcn_global_load_lds(
        (const __attribute__((address_space(1))) unsigned int*)(uintptr_t)gptr,
        (__attribute__((address_space(3))) unsigned int*)(unsigned)(uintptr_t)lptr,
        16, 0, 0);
}

// One wave per row: fp32 diag dot, hi/lo bf16 split, stats init.
__global__ __launch_bounds__(256) void prep_kernel(const float* __restrict__ im,
                                                   const float* __restrict__ s){
    const int w    = threadIdx.x >> 6;
    const int lane = threadIdx.x & 63;
    const int row  = blockIdx.x * 4 + w;

    const float4 a = ((const float4*)(im + (size_t)row * DDIM))[lane];
    const float4 b = ((const float4*)(s  + (size_t)row * DDIM))[lane];

    float dp = a.x*b.x + a.y*b.y + a.z*b.z + a.w*b.w;
    #pragma unroll
    for (int m = 1; m < 64; m <<= 1) dp += __shfl_xor(dp, m, 64);
    if (lane == 0){
        g_diag[row]   = dp;
        g_rowcnt[row] = 0u; g_rowkey[row] = 0u;
        g_colcnt[row] = 0u; g_colkey[row] = 0u;
    }

    float av[4] = {a.x, a.y, a.z, a.w};
    float bv[4] = {b.x, b.y, b.z, b.w};
    unsigned short ah[4], al[4], bh[4], bl[4];
    #pragma unroll
    for (int i = 0; i < 4; ++i){
        ah[i] = f2bf_rne(av[i]); al[i] = f2bf_rne(av[i] - bf2f(ah[i]));
        bh[i] = f2bf_rne(bv[i]); bl[i] = f2bf_rne(bv[i] - bf2f(bh[i]));
    }
    const size_t base = (size_t)row * K2 + lane * 4;
    *(ushort4*)&gA[base      ] = make_ushort4(ah[0], ah[1], ah[2], ah[3]);
    *(ushort4*)&gA[base + 256] = make_ushort4(al[0], al[1], al[2], al[3]);
    *(ushort4*)&gB[base      ] = make_ushort4(bh[0], bh[1], bh[2], bh[3]);
    *(ushort4*)&gB[base + 256] = make_ushort4(bl[0], bl[1], bl[2], bl[3]);
}

// 128x128 tile, 4 waves (2x2), 16x16x32 bf16 MFMA, BK=64 chunks over K=256.
// Per chunk: ONE staging phase (Ah->T1, Bh->T2, Bl->T3, 12 loads/thread),
// Al fragments loaded global->VGPR in MFMA A-layout (no barrier needed; issued
// right after the barrier, covered by pass1/2 MFMAs, consumed in pass3).
// 2 barriers per chunk (8/block, was 16). LDS XOR-swizzle (16B-chunk
// granularity) -> 0 bank conflicts. XCD-aware block swizzle for L2 locality.
__global__ __launch_bounds__(256, 3) void gemm_stats_kernel(){
    __shared__ unsigned short T1[128 * 64];   // Ah chunk
    __shared__ unsigned short T2[128 * 64];   // Bh chunk
    __shared__ unsigned short T3[128 * 64];   // Bl chunk
    __shared__ float drow[128];
    __shared__ float dcol[128];

    const int tid = threadIdx.x;
    const int bid = blockIdx.x;
    // bid[2:0]->band(XCD), bid[5:3]->row within band, bid[11:6]->column
    const int bi  = (bid & 7) * 8 + ((bid >> 3) & 7);
    const int bj  = bid >> 6;

    if (tid < 128) drow[tid]       = g_diag[bi * 128 + tid];
    else           dcol[tid - 128] = g_diag[bj * 128 + (tid - 128)];

    const int w    = tid >> 6, lane = tid & 63;
    const int wm   = w >> 1,   wn   = w & 1;
    const int quad = lane >> 4, l16 = lane & 15;
    const int sw   = l16 & 7;           // read-side swizzle key

    floatx4 acc[4][4] = {};

    const unsigned short* Abase = gA + (size_t)bi * 128 * K2;
    const unsigned short* Bbase = gB + (size_t)bj * 128 * K2;
    // Al fragment base for this wave/lane: row = wm*64 + mi*16 + l16, lo half.
    const unsigned short* AloFrag = Abase + (size_t)(wm * 64 + l16) * K2 + 256 + quad * 8;

    #pragma unroll 1
    for (int kc = 0; kc < 4; ++kc){
        // ---- stage Ah -> T1, Bh -> T2, Bl -> T3 (single deep phase) ----
        #pragma unroll
        for (int q = 0; q < 4; ++q){
            const int o    = q * 4096 + tid * 16;     // LDS byte offset (fixed)
            const int ch   = o >> 4;                  // linear chunk index
            const int r    = ch >> 3;                 // tile row
            const int clog = (ch & 7) ^ (r & 7);      // stored -> logical chunk
            const size_t goff = (size_t)r * K2 + kc * 64 + clog * 8;
            load_lds16(Abase + goff,       (char*)T1 + o);
            load_lds16(Bbase + goff,       (char*)T2 + o);
            load_lds16(Bbase + goff + 256, (char*)T3 + o);
        }
        __syncthreads();

        // ---- issue Al global->VGPR fragment loads (overlap with pass1/2) ----
        short8 alf[2][4];
        #pragma unroll
        for (int ks = 0; ks < 2; ++ks)
            #pragma unroll
            for (int mi = 0; mi < 4; ++mi)
                alf[ks][mi] = *(const short8*)(AloFrag + (size_t)(mi * 16) * K2 + kc * 64 + ks * 32);

        // ---- pass 1+2: Ah*Bh + Ah*Bl ----
        #pragma unroll
        for (int ks = 0; ks < 2; ++ks){
            const int co = ((ks * 4 + quad) ^ sw) * 8;
            short8 ahf[4], bhf[4], blf[4];
            #pragma unroll
            for (int mi = 0; mi < 4; ++mi)
                ahf[mi] = *(const short8*)&T1[(wm * 64 + mi * 16 + l16) * 64 + co];
            #pragma unroll
            for (int nj = 0; nj < 4; ++nj){
                bhf[nj] = *(const short8*)&T2[(wn * 64 + nj * 16 + l16) * 64 + co];
                blf[nj] = *(const short8*)&T3[(wn * 64 + nj * 16 + l16) * 64 + co];
            }
            #pragma unroll
            for (int mi = 0; mi < 4; ++mi)
                #pragma unroll
                for (int nj = 0; nj < 4; ++nj)
                    acc[mi][nj] = __builtin_amdgcn_mfma_f32_16x16x32_bf16(ahf[mi], bhf[nj], acc[mi][nj], 0, 0, 0);
            #pragma unroll
            for (int mi = 0; mi < 4; ++mi)
                #pragma unroll
                for (int nj = 0; nj < 4; ++nj)
                    acc[mi][nj] = __builtin_amdgcn_mfma_f32_16x16x32_bf16(ahf[mi], blf[nj], acc[mi][nj], 0, 0, 0);
        }

        // ---- pass 3: Al*Bh (Al from registers, Bh still in T2) ----
        #pragma unroll
        for (int ks = 0; ks < 2; ++ks){
            const int co = ((ks * 4 + quad) ^ sw) * 8;
            short8 bhf[4];
            #pragma unroll
            for (int nj = 0; nj < 4; ++nj)
                bhf[nj] = *(const short8*)&T2[(wn * 64 + nj * 16 + l16) * 64 + co];
            #pragma unroll
            for (int mi = 0; mi < 4; ++mi)
                #pragma unroll
                for (int nj = 0; nj < 4; ++nj)
                    acc[mi][nj] = __builtin_amdgcn_mfma_f32_16x16x32_bf16(alf[ks][mi], bhf[nj], acc[mi][nj], 0, 0, 0);
        }
        __syncthreads();
    }

    // ---- fused stats epilogue ----
    // C/D layout (verified m89/m91): col = lane&15, row = quad*4 + reg.
    const int colbase = bj * 128 + wn * 64;
    const int rowbase = bi * 128 + wm * 64;

    // row stats: reduce across cols (lanes differing in bits 0..3)
    #pragma unroll
    for (int mi = 0; mi < 4; ++mi){
        #pragma unroll
        for (int r = 0; r < 4; ++r){
            const int lrow = wm * 64 + mi * 16 + quad * 4 + r;
            const int gi   = bi * 128 + lrow;
            const float dv = drow[lrow];
            int cnt = 0; float mx = -3.0e38f;
            #pragma unroll
            for (int nj = 0; nj < 4; ++nj){
                const float v  = acc[mi][nj][r];
                const int   gj = colbase + nj * 16 + l16;
                if (gi != gj){                 // exclude diagonal explicitly
                    cnt += (v < dv) ? 1 : 0;
                    mx = fmaxf(mx, v);
                }
            }
            #pragma unroll
            for (int m = 1; m < 16; m <<= 1){
                cnt += __shfl_xor(cnt, m, 64);
                mx   = fmaxf(mx, __shfl_xor(mx, m, 64));
            }
            if (l16 == 0){
                atomicAdd(&g_rowcnt[gi], (unsigned)cnt);
                atomicMax(&g_rowkey[gi], fkey(mx));
            }
        }
    }
    // col stats: reduce across rows (lanes differing in bits 4..5, plus regs)
    #pragma unroll
    for (int nj = 0; nj < 4; ++nj){
        const int lcol = wn * 64 + nj * 16 + l16;
        const int gj   = bj * 128 + lcol;
        const float dv = dcol[lcol];
        int cnt = 0; float mx = -3.0e38f;
        #pragma unroll
        for (int mi = 0; mi < 4; ++mi){
            #pragma unroll
            for (int r = 0; r < 4; ++r){
                const float v  = acc[mi][nj][r];
                const int   gi = rowbase + mi * 16 + quad * 4 + r;
                if (gi != gj){
                    cnt += (v < dv) ? 1 : 0;
                    mx = fmaxf(mx, v);
                }
            }
        }
        #pragma unroll
        for (int m = 16; m < 64; m <<= 1){
            cnt += __shfl_xor(cnt, m, 64);
            mx   = fmaxf(mx, __shfl_xor(mx, m, 64));
        }
        if (quad == 0){
            atomicAdd(&g_colcnt[gj], (unsigned)cnt);
            atomicMax(&g_colkey[gj], fkey(mx));
        }
    }
}

__global__ __launch_bounds__(256) void finalize_kernel(float* __restrict__ out){
    __shared__ double red[256];
    double acc = 0.0;
    for (int i = threadIdx.x; i < NROWS; i += 256){
        const float d  = g_diag[i];
        const float cs  = fmaxf(MARGIN_F + kinv(g_rowkey[i]) - d, 0.0f) * (1.0f / (float)(g_rowcnt[i] + 1u));
        const float cim = fmaxf(MARGIN_F + kinv(g_colkey[i]) - d, 0.0f) * (1.0f / (float)(g_colcnt[i] + 1u));
        acc += (double)cs + (double)cim;
    }
    red[threadIdx.x] = acc;
    __syncthreads();
    for (int s2 = 128; s2 > 0; s2 >>= 1){
        if (threadIdx.x < s2) red[threadIdx.x] += red[threadIdx.x + s2];
        __syncthreads();
    }
    if (threadIdx.x == 0) out[0] = (float)red[0];
}

extern "C" void kernel_launch(void* const* d_in, const int* in_sizes, int n_in,
                              void* d_out, int out_size, void* d_ws, size_t ws_size,
                              hipStream_t stream){
    const float* im = (const float*)d_in[0];
    const float* s  = (const float*)d_in[1];
    float* out = (float*)d_out;

    prep_kernel<<<NROWS / 4, 256, 0, stream>>>(im, s);
    gemm_stats_kernel<<<4096, 256, 0, stream>>>();
    finalize_kernel<<<1, 256, 0, stream>>>(out);
}

// Round 5
// 251.780 us; speedup vs baseline: 1.8744x; 1.0214x over previous
//
#include <hip/hip_runtime.h>
#include <stdint.h>

#define NROWS 8192
#define DDIM  256
#define K2    512          // [hi | lo] packed per row
#define MARGIN_F 0.2f

typedef short  short8  __attribute__((ext_vector_type(8)));
typedef float  floatx4 __attribute__((ext_vector_type(4)));

// Static device buffers (avoid depending on ws_size).
__device__ unsigned short gA[(size_t)NROWS * K2];   // im split: [hi | lo]
__device__ unsigned short gB[(size_t)NROWS * K2];   // s  split: [hi | lo]
__device__ float    g_diag[NROWS];
__device__ unsigned g_rowcnt[NROWS];
__device__ unsigned g_rowkey[NROWS];
__device__ unsigned g_colcnt[NROWS];
__device__ unsigned g_colkey[NROWS];

__device__ __forceinline__ unsigned short f2bf_rne(float x){
    unsigned u = __float_as_uint(x);
    return (unsigned short)((u + 0x7FFFu + ((u >> 16) & 1u)) >> 16);
}
__device__ __forceinline__ float bf2f(unsigned short h){
    return __uint_as_float(((unsigned)h) << 16);
}
// monotone float -> uint key (order-preserving), so atomicMax works on floats
__device__ __forceinline__ unsigned fkey(float f){
    unsigned u = __float_as_uint(f);
    return (u & 0x80000000u) ? ~u : (u | 0x80000000u);
}
__device__ __forceinline__ float kinv(unsigned k){
    unsigned u = (k & 0x80000000u) ? (k ^ 0x80000000u) : ~k;
    return __uint_as_float(u);
}

__device__ __forceinline__ void load_lds16(const unsigned short* gptr, void* lptr){
    __builtin_amdgcn_global_load_lds(
        (const __attribute__((address_space(1))) unsigned int*)(uintptr_t)gptr,
        (__attribute__((address_space(3))) unsigned int*)(unsigned)(uintptr_t)lptr,
        16, 0, 0);
}

// One wave per row: fp32 diag dot, hi/lo bf16 split, stats init.
__global__ __launch_bounds__(256) void prep_kernel(const float* __restrict__ im,
                                                   const float* __restrict__ s){
    const int w    = threadIdx.x >> 6;
    const int lane = threadIdx.x & 63;
    const int row  = blockIdx.x * 4 + w;

    const float4 a = ((const float4*)(im + (size_t)row * DDIM))[lane];
    const float4 b = ((const float4*)(s  + (size_t)row * DDIM))[lane];

    float dp = a.x*b.x + a.y*b.y + a.z*b.z + a.w*b.w;
    #pragma unroll
    for (int m = 1; m < 64; m <<= 1) dp += __shfl_xor(dp, m, 64);
    if (lane == 0){
        g_diag[row]   = dp;
        g_rowcnt[row] = 0u; g_rowkey[row] = 0u;
        g_colcnt[row] = 0u; g_colkey[row] = 0u;
    }

    float av[4] = {a.x, a.y, a.z, a.w};
    float bv[4] = {b.x, b.y, b.z, b.w};
    unsigned short ah[4], al[4], bh[4], bl[4];
    #pragma unroll
    for (int i = 0; i < 4; ++i){
        ah[i] = f2bf_rne(av[i]); al[i] = f2bf_rne(av[i] - bf2f(ah[i]));
        bh[i] = f2bf_rne(bv[i]); bl[i] = f2bf_rne(bv[i] - bf2f(bh[i]));
    }
    const size_t base = (size_t)row * K2 + lane * 4;
    *(ushort4*)&gA[base      ] = make_ushort4(ah[0], ah[1], ah[2], ah[3]);
    *(ushort4*)&gA[base + 256] = make_ushort4(al[0], al[1], al[2], al[3]);
    *(ushort4*)&gB[base      ] = make_ushort4(bh[0], bh[1], bh[2], bh[3]);
    *(ushort4*)&gB[base + 256] = make_ushort4(bl[0], bl[1], bl[2], bl[3]);
}

// 128x128 tile, 4 waves (2x2), 16x16x32 bf16 MFMA.
// BK=32 chunks (8 over K=256), DOUBLE-BUFFERED LDS staging: per chunk,
//   barrier -> Al reg-loads (issued FIRST so their vmcnt wait doesn't FIFO-drain
//   the stage) -> stage chunk k+1 into other buffer -> compute 48 MFMA on
//   current buffer. The barrier's vmcnt(0) drain is covered by a full compute
//   phase. LDS swizzle for 64B rows: chunk key (row>>1)&3 + row parity spreads
//   8 consecutive lanes over all 32 banks (2-way/16-lane = free).
__global__ __launch_bounds__(256, 3) void gemm_stats_kernel(){
    __shared__ unsigned short A0[128 * 32], B0[128 * 32], C0[128 * 32];  // buf0: Ah,Bh,Bl
    __shared__ unsigned short A1[128 * 32], B1[128 * 32], C1[128 * 32];  // buf1
    __shared__ float drow[128];
    __shared__ float dcol[128];

    const int tid = threadIdx.x;
    const int bid = blockIdx.x;
    // bid[2:0]->band(XCD), bid[5:3]->row within band, bid[11:6]->column
    const int bi  = (bid & 7) * 8 + ((bid >> 3) & 7);
    const int bj  = bid >> 6;

    if (tid < 128) drow[tid]       = g_diag[bi * 128 + tid];
    else           dcol[tid - 128] = g_diag[bj * 128 + (tid - 128)];

    const int w    = tid >> 6, lane = tid & 63;
    const int wm   = w >> 1,   wn   = w & 1;
    const int quad = lane >> 4, l16 = lane & 15;
    const int k2key = (l16 >> 1) & 3;           // read-side swizzle key
    const int coA   = (quad ^ k2key) * 8;       // chunk offset within 32-short row

    floatx4 acc[4][4] = {};

    const unsigned short* Abase = gA + (size_t)bi * 128 * K2;
    const unsigned short* Bbase = gB + (size_t)bj * 128 * K2;
    // Al fragment base: row = wm*64 + mi*16 + l16, lo half (+256), K-seg quad*8.
    const unsigned short* AloFrag = Abase + (size_t)(wm * 64 + l16) * K2 + 256 + quad * 8;

    // row base offsets (in shorts) into 128x32 tiles
    const int arow = (wm * 64 + l16) * 32 + coA;
    const int brow = (wn * 64 + l16) * 32 + coA;

    // ---- staging: thread tid covers chunks {tid, 256+tid} of each 8KB tile ----
#define STAGE(kb, Ta, Tb, Tc)                                              \
    {                                                                      \
        _Pragma("unroll")                                                  \
        for (int q = 0; q < 2; ++q){                                       \
            const int ch   = q * 256 + tid;                                \
            const int r    = ch >> 2;                                      \
            const int clog = (ch & 3) ^ ((r >> 1) & 3);                    \
            const size_t goff = (size_t)r * K2 + (kb) + clog * 8;          \
            const int o = ch * 16;                                         \
            load_lds16(Abase + goff,       (char*)(Ta) + o);               \
            load_lds16(Bbase + goff,       (char*)(Tb) + o);               \
            load_lds16(Bbase + goff + 256, (char*)(Tc) + o);               \
        }                                                                  \
    }

#define COMPUTE(Ta, Tb, Tc, ALF)                                           \
    {                                                                      \
        short8 ahf[4], bhf[4], blf[4];                                     \
        _Pragma("unroll")                                                  \
        for (int mi = 0; mi < 4; ++mi)                                     \
            ahf[mi] = *(const short8*)&(Ta)[arow + mi * 512];              \
        _Pragma("unroll")                                                  \
        for (int nj = 0; nj < 4; ++nj){                                    \
            bhf[nj] = *(const short8*)&(Tb)[brow + nj * 512];              \
            blf[nj] = *(const short8*)&(Tc)[brow + nj * 512];              \
        }                                                                  \
        _Pragma("unroll")                                                  \
        for (int mi = 0; mi < 4; ++mi)                                     \
            _Pragma("unroll")                                              \
            for (int nj = 0; nj < 4; ++nj)                                 \
                acc[mi][nj] = __builtin_amdgcn_mfma_f32_16x16x32_bf16(ahf[mi], bhf[nj], acc[mi][nj], 0, 0, 0); \
        _Pragma("unroll")                                                  \
        for (int mi = 0; mi < 4; ++mi)                                     \
            _Pragma("unroll")                                              \
            for (int nj = 0; nj < 4; ++nj)                                 \
                acc[mi][nj] = __builtin_amdgcn_mfma_f32_16x16x32_bf16(ahf[mi], blf[nj], acc[mi][nj], 0, 0, 0); \
        _Pragma("unroll")                                                  \
        for (int mi = 0; mi < 4; ++mi)                                     \
            _Pragma("unroll")                                              \
            for (int nj = 0; nj < 4; ++nj)                                 \
                acc[mi][nj] = __builtin_amdgcn_mfma_f32_16x16x32_bf16((ALF)[mi], bhf[nj], acc[mi][nj], 0, 0, 0); \
    }

#define LOAD_ALF(ALF, kc)                                                  \
    {                                                                      \
        _Pragma("unroll")                                                  \
        for (int mi = 0; mi < 4; ++mi)                                     \
            (ALF)[mi] = *(const short8*)(AloFrag + (size_t)(mi * 16) * K2 + (kc) * 32); \
    }

    STAGE(0, A0, B0, C0);

    #pragma unroll 1
    for (int kp = 0; kp < 4; ++kp){
        const int kc0 = kp * 2, kc1 = kp * 2 + 1;
        short8 alf[4];

        __syncthreads();                       // buf0 ready (drain covered by prev compute)
        LOAD_ALF(alf, kc0);                    // issue reg loads FIRST (vmcnt FIFO)
        STAGE(kc1 * 32, A1, B1, C1);           // prefetch next chunk -> buf1
        COMPUTE(A0, B0, C0, alf);

        __syncthreads();                       // buf1 ready
        LOAD_ALF(alf, kc1);
        if (kp < 3) STAGE((kc1 + 1) * 32, A0, B0, C0);
        COMPUTE(A1, B1, C1, alf);
    }

    // ---- fused stats epilogue ----
    // C/D layout (verified m89/m91): col = lane&15, row = quad*4 + reg.
    const int colbase = bj * 128 + wn * 64;
    const int rowbase = bi * 128 + wm * 64;

    // row stats: reduce across cols (lanes differing in bits 0..3)
    #pragma unroll
    for (int mi = 0; mi < 4; ++mi){
        #pragma unroll
        for (int r = 0; r < 4; ++r){
            const int lrow = wm * 64 + mi * 16 + quad * 4 + r;
            const int gi   = bi * 128 + lrow;
            const float dv = drow[lrow];
            int cnt = 0; float mx = -3.0e38f;
            #pragma unroll
            for (int nj = 0; nj < 4; ++nj){
                const float v  = acc[mi][nj][r];
                const int   gj = colbase + nj * 16 + l16;
                if (gi != gj){                 // exclude diagonal explicitly
                    cnt += (v < dv) ? 1 : 0;
                    mx = fmaxf(mx, v);
                }
            }
            #pragma unroll
            for (int m = 1; m < 16; m <<= 1){
                cnt += __shfl_xor(cnt, m, 64);
                mx   = fmaxf(mx, __shfl_xor(mx, m, 64));
            }
            if (l16 == 0){
                atomicAdd(&g_rowcnt[gi], (unsigned)cnt);
                atomicMax(&g_rowkey[gi], fkey(mx));
            }
        }
    }
    // col stats: reduce across rows (lanes differing in bits 4..5, plus regs)
    #pragma unroll
    for (int nj = 0; nj < 4; ++nj){
        const int lcol = wn * 64 + nj * 16 + l16;
        const int gj   = bj * 128 + lcol;
        const float dv = dcol[lcol];
        int cnt = 0; float mx = -3.0e38f;
        #pragma unroll
        for (int mi = 0; mi < 4; ++mi){
            #pragma unroll
            for (int r = 0; r < 4; ++r){
                const float v  = acc[mi][nj][r];
                const int   gi = rowbase + mi * 16 + quad * 4 + r;
                if (gi != gj){
                    cnt += (v < dv) ? 1 : 0;
                    mx = fmaxf(mx, v);
                }
            }
        }
        #pragma unroll
        for (int m = 16; m < 64; m <<= 1){
            cnt += __shfl_xor(cnt, m, 64);
            mx   = fmaxf(mx, __shfl_xor(mx, m, 64));
        }
        if (quad == 0){
            atomicAdd(&g_colcnt[gj], (unsigned)cnt);
            atomicMax(&g_colkey[gj], fkey(mx));
        }
    }
#undef STAGE
#undef COMPUTE
#undef LOAD_ALF
}

__global__ __launch_bounds__(256) void finalize_kernel(float* __restrict__ out){
    __shared__ double red[256];
    double acc = 0.0;
    #pragma unroll
    for (int it = 0; it < NROWS / 256; ++it){
        const int i = it * 256 + threadIdx.x;
        const float d  = g_diag[i];
        const float cs  = fmaxf(MARGIN_F + kinv(g_rowkey[i]) - d, 0.0f) * (1.0f / (float)(g_rowcnt[i] + 1u));
        const float cim = fmaxf(MARGIN_F + kinv(g_colkey[i]) - d, 0.0f) * (1.0f / (float)(g_colcnt[i] + 1u));
        acc += (double)cs + (double)cim;
    }
    red[threadIdx.x] = acc;
    __syncthreads();
    for (int s2 = 128; s2 > 0; s2 >>= 1){
        if (threadIdx.x < s2) red[threadIdx.x] += red[threadIdx.x + s2];
        __syncthreads();
    }
    if (threadIdx.x == 0) out[0] = (float)red[0];
}

extern "C" void kernel_launch(void* const* d_in, const int* in_sizes, int n_in,
                              void* d_out, int out_size, void* d_ws, size_t ws_size,
                              hipStream_t stream){
    const float* im = (const float*)d_in[0];
    const float* s  = (const float*)d_in[1];
    float* out = (float*)d_out;

    prep_kernel<<<NROWS / 4, 256, 0, stream>>>(im, s);
    gemm_stats_kernel<<<4096, 256, 0, stream>>>();
    finalize_kernel<<<1, 256, 0, stream>>>(out);
}